// Round 13
// baseline (905.348 us; speedup 1.0000x reference)
//
#include <hip/hip_runtime.h>
#include <math.h>

#define N_PATHS 50000
#define N_LINKS 10000
#define LPATH   8
#define DEG     40
#define DIM     64
#define G3      192
#define ITERS   8
#define LXP     200   // LDS LX row pitch in ushorts (400B): 2-way bank conflicts only

typedef float f32x4  __attribute__((ext_vector_type(4)));
typedef short bf16x8 __attribute__((ext_vector_type(8)));

__device__ __forceinline__ float fsigmoid(float x){ return 1.0f/(1.0f + __expf(-x)); }
__device__ __forceinline__ float ftanh(float x){ return 1.0f - 2.0f/(__expf(2.0f*x) + 1.0f); }
__device__ __forceinline__ unsigned short bf16_rne(float v){
  unsigned u = __float_as_uint(v);
  return (unsigned short)((u + 0x7FFFu + ((u>>16)&1u)) >> 16);
}
__device__ __forceinline__ unsigned pack_bf16(float a, float b){
  unsigned r;
  asm("v_cvt_pk_bf16_f32 %0, %1, %2" : "=v"(r) : "v"(a), "v"(b));
  return r;
}
__device__ __forceinline__ float lo16f(unsigned v){ return __uint_as_float(v << 16); }
__device__ __forceinline__ float hi16f(unsigned v){ return __uint_as_float(v & 0xFFFF0000u); }
__device__ __forceinline__ void split8(const float* s, bf16x8& hi, bf16x8& lo){
  #pragma unroll
  for (int e=0;e<8;e++){
    unsigned short hb = bf16_rne(s[e]);
    float lof = s[e] - __uint_as_float(((unsigned)hb)<<16);
    hi[e] = (short)hb; lo[e] = (short)bf16_rne(lof);
  }
}
__device__ __forceinline__ void accum8(float* a, uint4 v){
  unsigned x[4] = {v.x, v.y, v.z, v.w};
  #pragma unroll
  for (int q=0;q<4;q++){
    a[2*q]   += __uint_as_float((x[q]&0xFFFFu)<<16);
    a[2*q+1] += __uint_as_float(x[q]&0xFFFF0000u);
  }
}

// ---------------- path embedding ----------------
__global__ __launch_bounds__(256) void path_embed(
    const float* __restrict__ ft, const float* __restrict__ fp, const float* __restrict__ fps,
    const float* __restrict__ w1, const float* __restrict__ b1,
    const float* __restrict__ w2, const float* __restrict__ b2,
    float* __restrict__ path_state)
{
  __shared__ float h1[4][DIM];
  int j  = threadIdx.x & 63;
  int pl = threadIdx.x >> 6;
  int p  = blockIdx.x*4 + pl;
  float x0 = ft[p]*1e-4f, x1 = fp[p]*1e-3f, x2 = fps[p]*1e-3f;
  float h = b1[j] + x0*w1[0*DIM+j] + x1*w1[1*DIM+j] + x2*w1[2*DIM+j];
  h1[pl][j] = fmaxf(h, 0.f);
  __syncthreads();
  float acc = b2[j];
  #pragma unroll 8
  for (int k=0;k<DIM;k++) acc = fmaf(h1[pl][k], w2[k*DIM+j], acc);
  path_state[p*DIM+j] = fmaxf(acc, 0.f);
}

// ---------------- link embedding ----------------
__global__ __launch_bounds__(256) void link_embed(
    const float* __restrict__ ft, const float* __restrict__ cap, const int* __restrict__ ptl,
    const float* __restrict__ w1, const float* __restrict__ b1,
    const float* __restrict__ w2, const float* __restrict__ b2,
    float* __restrict__ link_state)
{
  __shared__ float h1[4][DIM];
  int j  = threadIdx.x & 63;
  int wl = threadIdx.x >> 6;
  int l  = blockIdx.x*4 + wl;
  float s = 0.f;
  if (j < DEG) s = ft[ptl[(l*DEG + j)*2 + 0]];
  #pragma unroll
  for (int off=32; off; off>>=1) s += __shfl_down(s, off);
  float load = __shfl(s, 0) / (cap[l]*1e9f);
  float x0 = cap[l]*1e-5f;
  float h = b1[j] + x0*w1[0*DIM+j] + load*w1[1*DIM+j];
  h1[wl][j] = fmaxf(h, 0.f);
  __syncthreads();
  float acc = b2[j];
  #pragma unroll 8
  for (int k=0;k<DIM;k++) acc = fmaf(h1[wl][k], w2[k*DIM+j], acc);
  link_state[l*DIM+j] = fmaxf(acc, 0.f);
}

// ---------------- pack 4 weight mats into bf16 MFMA fragments ----------------
__global__ __launch_bounds__(256) void pack_frags(
    const float* __restrict__ pg_wh, const float* __restrict__ pg_wx,
    const float* __restrict__ lg_wx, const float* __restrict__ lg_wh,
    unsigned short* __restrict__ whf)
{
  int tid = blockIdx.x*256 + threadIdx.x;
  if (tid >= 4*24*512) return;
  int i = tid & 7, l = (tid>>3)&63, f = (tid>>9)%24, m = tid/(24*512);
  int nt = f>>1, kc = f&1;
  int k = kc*32 + (l>>4)*8 + i;
  int n = nt*16 + (l&15);
  const float* src = (m==0)?pg_wh : (m==1)?pg_wx : (m==2)?lg_wx : lg_wh;
  whf[tid] = bf16_rne(src[k*G3 + n]);
}

// ---------------- initial LX, packed bf16 [dim][z,r,q], 384 B/link ----------------
__global__ __launch_bounds__(192) void compute_lx(
    const float* __restrict__ link_state, const float* __restrict__ wx,
    const float* __restrict__ bx, const float* __restrict__ bh,
    unsigned short* __restrict__ LXq)
{
  __shared__ float ls[4][DIM];
  int g  = threadIdx.x;
  int l0 = blockIdx.x*4;
  if (g < DIM){
    #pragma unroll
    for (int li=0; li<4; li++) ls[li][g] = link_state[(l0+li)*DIM+g];
  }
  __syncthreads();
  float b = bx[g] + (g < 128 ? bh[g] : 0.f);
  float a0=b, a1=b, a2=b, a3=b;
  #pragma unroll 8
  for (int k=0;k<DIM;k++){
    float w = wx[k*G3+g];
    a0 = fmaf(ls[0][k], w, a0);
    a1 = fmaf(ls[1][k], w, a1);
    a2 = fmaf(ls[2][k], w, a2);
    a3 = fmaf(ls[3][k], w, a3);
  }
  int comp = g >> 6, dim = g & 63;
  int pos = dim*3 + comp;
  LXq[(size_t)(l0+0)*G3+pos]=bf16_rne(a0);
  LXq[(size_t)(l0+1)*G3+pos]=bf16_rne(a1);
  LXq[(size_t)(l0+2)*G3+pos]=bf16_rne(a2);
  LXq[(size_t)(l0+3)*G3+pos]=bf16_rne(a3);
}

// ---------------- MFMA 8-step GRU scan: COALESCED LX staging through LDS ----------------
// block = 4 waves, ONE 16-path tile, n-split (wave w owns dims w*16..+15).
// Per step, the 16 needed LX rows are staged into LDS by 24-consecutive-lane uint4 loads
// (TA-coalesced segments) instead of per-lane divergent gathers; ds_write lands them
// late (T14), raw lgkm barrier keeps seq16 stores un-drained.
__global__ __launch_bounds__(256) void path_scan_mfma(
    const unsigned short* __restrict__ LXq, const int* __restrict__ ltp,
    const unsigned short* __restrict__ whf, const float* __restrict__ bh,
    float* __restrict__ path_state, unsigned short* __restrict__ seq16)
{
  __shared__ __align__(16) unsigned short lxb[2][16*LXP];   // 12.8 KB staged LX rows
  __shared__ __align__(16) unsigned short htile[2][16*72];  // 4.6 KB h (bf16)
  __shared__ int ltps[128];
  int tid = threadIdx.x, l = tid & 63, w = tid >> 6;
  int lg = l >> 4, lr = l & 15;
  int p0 = blockIdx.x*16;                 // 50000/16 = 3125 exact

  // this wave's 6 W-fragments of pg_wh (nt = w, w+4, w+8 -> z, r, q)
  bf16x8 bf[3][2];
  #pragma unroll
  for (int j=0;j<3;j++){
    int nt = w + j*4;
    bf[j][0] = *(const bf16x8*)(whf + (size_t)(nt*2+0)*512 + l*8);
    bf[j][1] = *(const bf16x8*)(whf + (size_t)(nt*2+1)*512 + l*8);
  }
  float bhq[4];
  #pragma unroll
  for (int r=0;r<4;r++) bhq[r] = bh[128 + w*16 + lg*4 + r];

  if (tid < 128) ltps[tid] = ltp[(size_t)p0*LPATH + tid];

  // stage h -> htile[0] bf16 (coalesced float4 reads, packed 8B LDS writes)
  {
    int pi = tid >> 4, c4 = (tid & 15)*4;
    float4 v = *(const float4*)(path_state + (size_t)(p0+pi)*DIM + c4);
    uint2 u = make_uint2(pack_bf16(v.x, v.y), pack_bf16(v.z, v.w));
    *(uint2*)&htile[0][pi*72 + c4] = u;
  }
  f32x4 hold = *(const f32x4*)(path_state + (size_t)(p0+lr)*DIM + w*16 + lg*4);

  __syncthreads();   // ltps + htile visible

  // stage t=0 LX rows: wave w stages rows 4w..4w+3, 24 lanes x uint4 (coalesced)
  {
    #pragma unroll
    for (int i=0;i<4;i++){
      int row = w*4 + i;
      int lk = ltps[row*LPATH + 0];
      if (l < 24){
        uint4 v = *(const uint4*)(LXq + (size_t)lk*G3 + l*8);
        *(uint4*)&lxb[0][row*LXP + l*8] = v;
      }
    }
  }
  __syncthreads();

  unsigned short* seqp = seq16 + ((size_t)(p0+lr)*LPATH)*DIM + w*16 + lg*4;
  const int lxoff = w*48 + lg*12;   // ushort offset of this lane's 4 dims within a row
  int cur = 0;

  for (int t=0; t<LPATH; t++){
    // 1) issue NEXT step's LX row loads (coalesced 24-lane uint4, consumed late)
    int tn = (t < LPATH-1) ? t+1 : t;
    uint4 ld[4];
    #pragma unroll
    for (int i=0;i<4;i++){
      int lk = ltps[(w*4+i)*LPATH + tn];
      if (l < 24) ld[i] = *(const uint4*)(LXq + (size_t)lk*G3 + l*8);
    }
    __builtin_amdgcn_sched_barrier(0);   // pin load issue before compute

    // 2) h fragments + 6 MFMAs (LDS-only deps)
    bf16x8 h0 = *(const bf16x8*)&htile[cur][lr*72 +  0 + lg*8];
    bf16x8 h1 = *(const bf16x8*)&htile[cur][lr*72 + 32 + lg*8];
    f32x4 accz = (f32x4){0.f,0.f,0.f,0.f};
    f32x4 accr = (f32x4){0.f,0.f,0.f,0.f};
    f32x4 accq = (f32x4){bhq[0],bhq[1],bhq[2],bhq[3]};
    accz = __builtin_amdgcn_mfma_f32_16x16x32_bf16(bf[0][0], h0, accz, 0,0,0);
    accr = __builtin_amdgcn_mfma_f32_16x16x32_bf16(bf[1][0], h0, accr, 0,0,0);
    accq = __builtin_amdgcn_mfma_f32_16x16x32_bf16(bf[2][0], h0, accq, 0,0,0);
    accz = __builtin_amdgcn_mfma_f32_16x16x32_bf16(bf[0][1], h1, accz, 0,0,0);
    accr = __builtin_amdgcn_mfma_f32_16x16x32_bf16(bf[1][1], h1, accr, 0,0,0);
    accq = __builtin_amdgcn_mfma_f32_16x16x32_bf16(bf[2][1], h1, accq, 0,0,0);

    // 3) gates: LX from staged LDS (row lr, this lane's 4 dims; 2-way conflicts = free)
    const unsigned short* myx = &lxb[cur][lr*LXP + lxoff];
    uint2 c0 = *(const uint2*)(myx);
    uint2 c1 = *(const uint2*)(myx+4);
    uint2 c2 = *(const uint2*)(myx+8);
    float lz[4]  = { lo16f(c0.x), hi16f(c0.y), lo16f(c1.y), hi16f(c2.x) };
    float lrr[4] = { hi16f(c0.x), lo16f(c1.x), hi16f(c1.y), lo16f(c2.y) };
    float lq[4]  = { lo16f(c0.y), hi16f(c1.x), lo16f(c2.x), hi16f(c2.y) };
    f32x4 hn;
    #pragma unroll
    for (int r=0;r<4;r++){
      float z  = fsigmoid(lz[r]  + accz[r]);
      float rr = fsigmoid(lrr[r] + accr[r]);
      float hh = ftanh(lq[r] + rr*accq[r]);
      hn[r] = z*hold[r] + (1.f-z)*hh;
    }
    hold = hn;
    uint2 u = make_uint2(pack_bf16(hn[0], hn[1]), pack_bf16(hn[2], hn[3]));
    *(uint2*)&htile[cur^1][lr*72 + w*16 + lg*4] = u;   // next-step h
    *(uint2*)(seqp + (size_t)t*DIM) = u;               // global store (never drained)

    // 4) land staged rows write-late (compiler inserts the vmcnt before these)
    #pragma unroll
    for (int i=0;i<4;i++){
      if (l < 24)
        *(uint4*)&lxb[cur^1][(w*4+i)*LXP + l*8] = ld[i];
    }

    // 5) raw barrier: LDS visibility only (lgkmcnt covers ds_writes); vmcnt stays counted
    __builtin_amdgcn_sched_barrier(0);
    asm volatile("s_waitcnt lgkmcnt(0)" ::: "memory");
    __builtin_amdgcn_s_barrier();
    __builtin_amdgcn_sched_barrier(0);

    cur ^= 1;
  }
  *(f32x4*)(path_state + (size_t)(p0+lr)*DIM + w*16 + lg*4) = hold;
}

// ---------------- fused link update: 4-wave parallel GRU + next LX ----------------
__global__ __launch_bounds__(256) void link_fused(
    const unsigned short* __restrict__ seq16, const int* __restrict__ ptl,
    const unsigned short* __restrict__ whf,
    const float* __restrict__ lbx, const float* __restrict__ lbh,
    const float* __restrict__ pbx, const float* __restrict__ pbh,
    float* __restrict__ link_state, unsigned short* __restrict__ LXq)
{
  __shared__ float pspart[4][16][64];
  __shared__ float tile[16*68];
  int tid = threadIdx.x, l = tid & 63, w = tid >> 6;
  int lr = l & 15, lg = l >> 4;
  int l0 = blockIdx.x*16;

  float ps[16];
  #pragma unroll
  for (int i=0;i<16;i++) ps[i]=0.f;
  {
    const int* pe = ptl + (size_t)(l0+lr)*DEG*2 + w*10*2;
    #pragma unroll
    for (int d=0; d<10; d++){
      int pp = pe[2*d], tt = pe[2*d+1];
      const unsigned short* rowp = seq16 + ((size_t)pp*LPATH + (tt-1))*DIM;
      accum8(ps,   *(const uint4*)(rowp + lg*8));
      accum8(ps+8, *(const uint4*)(rowp + 32 + lg*8));
    }
  }
  #pragma unroll
  for (int i=0;i<16;i++) pspart[w][i][l] = ps[i];
  __syncthreads();

  #pragma unroll
  for (int i=0;i<16;i++)
    ps[i] = pspart[0][i][l] + pspart[1][i][l] + pspart[2][i][l] + pspart[3][i][l];

  bf16x8 phi[2], plo[2], lhi[2], llo[2];
  #pragma unroll
  for (int kc=0;kc<2;kc++){
    split8(ps + kc*8, phi[kc], plo[kc]);
    float hs[8];
    const float* lsr = link_state + (size_t)(l0+lr)*DIM + kc*32 + lg*8;
    *(f32x4*)hs = *(const f32x4*)lsr;
    *(f32x4*)(hs+4) = *(const f32x4*)(lsr+4);
    split8(hs, lhi[kc], llo[kc]);
  }
  f32x4 mxa[3], mha[3];
  #pragma unroll
  for (int j=0;j<3;j++){
    int nt = w + j*4;
    float bxv = lbx[nt*16+lr], bhv = lbh[nt*16+lr];
    mxa[j] = (f32x4){bxv,bxv,bxv,bxv};
    mha[j] = (f32x4){bhv,bhv,bhv,bhv};
    #pragma unroll
    for (int kc=0;kc<2;kc++){
      bf16x8 bwx = *(const bf16x8*)(whf + (size_t)((2*24 + nt*2+kc)*512) + l*8);
      mxa[j] = __builtin_amdgcn_mfma_f32_16x16x32_bf16(phi[kc], bwx, mxa[j], 0,0,0);
      mxa[j] = __builtin_amdgcn_mfma_f32_16x16x32_bf16(plo[kc], bwx, mxa[j], 0,0,0);
      bf16x8 bwh = *(const bf16x8*)(whf + (size_t)((3*24 + nt*2+kc)*512) + l*8);
      mha[j] = __builtin_amdgcn_mfma_f32_16x16x32_bf16(lhi[kc], bwh, mha[j], 0,0,0);
      mha[j] = __builtin_amdgcn_mfma_f32_16x16x32_bf16(llo[kc], bwh, mha[j], 0,0,0);
    }
  }
  __syncthreads();

  #pragma unroll
  for (int r=0;r<4;r++){
    size_t lk = (size_t)(l0 + lg*4 + r)*DIM + w*16 + lr;
    float lsv = link_state[lk];
    float z  = fsigmoid(mxa[0][r] + mha[0][r]);
    float rr = fsigmoid(mxa[1][r] + mha[1][r]);
    float hh = ftanh(mxa[2][r] + rr*mha[2][r]);
    float hn = z*lsv + (1.f-z)*hh;
    link_state[lk] = hn;
    tile[(lg*4+r)*68 + w*16 + lr] = hn;
  }
  __syncthreads();

  f32x4 lxa[3];
  #pragma unroll
  for (int j=0;j<3;j++){
    int g = (w + j*4)*16 + lr;
    float b = pbx[g] + (g < 128 ? pbh[g] : 0.f);
    lxa[j] = (f32x4){b,b,b,b};
  }
  #pragma unroll
  for (int kc=0;kc<2;kc++){
    float hs[8];
    #pragma unroll
    for (int i=0;i<8;i++) hs[i] = tile[lr*68 + kc*32 + lg*8 + i];
    bf16x8 thi, tlo; split8(hs, thi, tlo);
    #pragma unroll
    for (int j=0;j<3;j++){
      int nt = w + j*4;
      bf16x8 bw = *(const bf16x8*)(whf + (size_t)((1*24 + nt*2+kc)*512) + l*8);
      lxa[j] = __builtin_amdgcn_mfma_f32_16x16x32_bf16(thi, bw, lxa[j], 0,0,0);
      lxa[j] = __builtin_amdgcn_mfma_f32_16x16x32_bf16(tlo, bw, lxa[j], 0,0,0);
    }
  }
  #pragma unroll
  for (int r=0;r<4;r++){
    int link = l0 + lg*4 + r;
    size_t base = (size_t)link*G3 + (size_t)(w*16 + lr)*3;
    LXq[base+0] = bf16_rne(lxa[0][r]);
    LXq[base+1] = bf16_rne(lxa[1][r]);
    LXq[base+2] = bf16_rne(lxa[2][r]);
  }
}

// ---------------- readout: LDS-staged coalesced reads (r10 known-good) ----------------
__global__ __launch_bounds__(256) void readout(
    const unsigned short* __restrict__ seq16, const int* __restrict__ ltp,
    const float* __restrict__ cap,
    const float* __restrict__ w1, const float* __restrict__ b1,
    const float* __restrict__ w2, const float* __restrict__ b2,
    const float* __restrict__ w3, const float* __restrict__ b3,
    float* __restrict__ out)
{
  __shared__ unsigned short rows_sh[4][64*72];
  __shared__ float w1s[DIM*32];
  __shared__ float w2s[32*16];
  __shared__ float w3s[16];
  __shared__ float b1s[32], b2s[16];
  int tid = threadIdx.x;
  for (int i=tid;i<DIM*32;i+=256) w1s[i]=w1[i];
  for (int i=tid;i<32*16;i+=256) w2s[i]=w2[i];
  if (tid<16) w3s[tid]=w3[tid];
  if (tid<32) b1s[tid]=b1[tid];
  if (tid<16) b2s[tid]=b2[tid];
  __syncthreads();

  int l = tid & 63, w = tid >> 6;
  size_t wave_r = (size_t)blockIdx.x*256 + (size_t)w*64;
  if (wave_r >= (size_t)N_PATHS*LPATH) return;

  const unsigned short* src = seq16 + wave_r*DIM;
  #pragma unroll
  for (int i=0;i<16;i++){
    int e  = i*64 + l;
    int ri = e >> 4;
    int c4 = e & 15;
    *(uint2*)&rows_sh[w][ri*72 + c4*4] = *(const uint2*)(src + (size_t)e*4);
  }

  size_t row = wave_r + l;
  const unsigned short* myrow = &rows_sh[w][l*72];
  float a[32];
  #pragma unroll
  for (int j=0;j<32;j++) a[j]=b1s[j];
  #pragma unroll
  for (int c=0;c<16;c++){
    uint2 v = *(const uint2*)(myrow + c*4);
    float f0 = __uint_as_float((v.x & 0xFFFFu) << 16);
    float f1 = __uint_as_float(v.x & 0xFFFF0000u);
    float f2 = __uint_as_float((v.y & 0xFFFFu) << 16);
    float f3 = __uint_as_float(v.y & 0xFFFF0000u);
    #pragma unroll
    for (int j=0;j<32;j++) a[j] = fmaf(f0, w1s[(c*4+0)*32+j], a[j]);
    #pragma unroll
    for (int j=0;j<32;j++) a[j] = fmaf(f1, w1s[(c*4+1)*32+j], a[j]);
    #pragma unroll
    for (int j=0;j<32;j++) a[j] = fmaf(f2, w1s[(c*4+2)*32+j], a[j]);
    #pragma unroll
    for (int j=0;j<32;j++) a[j] = fmaf(f3, w1s[(c*4+3)*32+j], a[j]);
  }
  float h2[16];
  #pragma unroll
  for (int j2=0;j2<16;j2++) h2[j2]=b2s[j2];
  #pragma unroll
  for (int j=0;j<32;j++){
    float hv = fmaxf(a[j],0.f);
    #pragma unroll
    for (int j2=0;j2<16;j2++) h2[j2] = fmaf(hv, w2s[j*16+j2], h2[j2]);
  }
  float o = b3[0];
  #pragma unroll
  for (int j2=0;j2<16;j2++) o = fmaf(fmaxf(h2[j2],0.f), w3s[j2], o);
  float sp = (o > 20.f) ? o : log1pf(__expf(o));
  float dly = sp / cap[ltp[row]];
  dly += __shfl_xor(dly, 1);
  dly += __shfl_xor(dly, 2);
  dly += __shfl_xor(dly, 4);
  if ((l & 7) == 0) out[row >> 3] = dly;
}

extern "C" void kernel_launch(void* const* d_in, const int* in_sizes, int n_in,
                              void* d_out, int out_size, void* d_ws, size_t ws_size,
                              hipStream_t stream) {
  const float* ft    = (const float*)d_in[0];
  const float* fpk   = (const float*)d_in[1];
  const float* fps   = (const float*)d_in[2];
  const float* cap   = (const float*)d_in[3];
  const int*   ltp   = (const int*)  d_in[4];
  const int*   ptl   = (const int*)  d_in[5];
  const float* pe_w1 = (const float*)d_in[6];
  const float* pe_b1 = (const float*)d_in[7];
  const float* pe_w2 = (const float*)d_in[8];
  const float* pe_b2 = (const float*)d_in[9];
  const float* le_w1 = (const float*)d_in[10];
  const float* le_b1 = (const float*)d_in[11];
  const float* le_w2 = (const float*)d_in[12];
  const float* le_b2 = (const float*)d_in[13];
  const float* pg_wx = (const float*)d_in[14];
  const float* pg_wh = (const float*)d_in[15];
  const float* pg_bx = (const float*)d_in[16];
  const float* pg_bh = (const float*)d_in[17];
  const float* lg_wx = (const float*)d_in[18];
  const float* lg_wh = (const float*)d_in[19];
  const float* lg_bx = (const float*)d_in[20];
  const float* lg_bh = (const float*)d_in[21];
  const float* ro_w1 = (const float*)d_in[22];
  const float* ro_b1 = (const float*)d_in[23];
  const float* ro_w2 = (const float*)d_in[24];
  const float* ro_b2 = (const float*)d_in[25];
  const float* ro_w3 = (const float*)d_in[26];
  const float* ro_b3 = (const float*)d_in[27];
  float* out = (float*)d_out;

  float* path_state = (float*)d_ws;
  float* link_state = path_state + (size_t)N_PATHS*DIM;
  unsigned short* LXq   = (unsigned short*)(link_state + (size_t)N_LINKS*DIM);  // 10000*192
  unsigned short* seq16 = LXq + (size_t)N_LINKS*G3;
  unsigned short* whf   = seq16 + (size_t)N_PATHS*LPATH*DIM;

  path_embed<<<N_PATHS/4, 256, 0, stream>>>(ft, fpk, fps, pe_w1, pe_b1, pe_w2, pe_b2, path_state);
  link_embed<<<N_LINKS/4, 256, 0, stream>>>(ft, cap, ptl, le_w1, le_b1, le_w2, le_b2, link_state);
  pack_frags<<<192, 256, 0, stream>>>(pg_wh, pg_wx, lg_wx, lg_wh, whf);
  compute_lx<<<N_LINKS/4, 192, 0, stream>>>(link_state, pg_wx, pg_bx, pg_bh, LXq);
  for (int it=0; it<ITERS; ++it){
    path_scan_mfma<<<N_PATHS/16, 256, 0, stream>>>(LXq, ltp, whf, pg_bh, path_state, seq16);
    if (it < ITERS-1)
      link_fused<<<N_LINKS/16, 256, 0, stream>>>(seq16, ptl, whf,
          lg_bx, lg_bh, pg_bx, pg_bh, link_state, LXq);
  }
  readout<<<(N_PATHS*LPATH + 255)/256, 256, 0, stream>>>(seq16, ltp, cap,
      ro_w1, ro_b1, ro_w2, ro_b2, ro_w3, ro_b3, out);
}

// Round 14
// 542.755 us; speedup vs baseline: 1.6681x; 1.6681x over previous
//
#include <hip/hip_runtime.h>
#include <math.h>

#define N_PATHS 50000
#define N_LINKS 10000
#define LPATH   8
#define DEG     40
#define DIM     64
#define G3      192
#define ITERS   8

typedef float f32x4  __attribute__((ext_vector_type(4)));
typedef short bf16x8 __attribute__((ext_vector_type(8)));

// fast gates: raw v_rcp_f32 (~1 ulp) instead of IEEE div (~10 VALU ops each).
// Gate outputs are bounded [0,1]; error is far below the bf16 rounding already applied.
__device__ __forceinline__ float fsigmoid(float x){
  return __builtin_amdgcn_rcpf(1.0f + __expf(-x));
}
__device__ __forceinline__ float ftanh(float x){
  return 1.0f - 2.0f*__builtin_amdgcn_rcpf(__expf(2.0f*x) + 1.0f);
}
__device__ __forceinline__ unsigned short bf16_rne(float v){
  unsigned u = __float_as_uint(v);
  return (unsigned short)((u + 0x7FFFu + ((u>>16)&1u)) >> 16);
}
__device__ __forceinline__ unsigned pack_bf16(float a, float b){
  unsigned r;
  asm("v_cvt_pk_bf16_f32 %0, %1, %2" : "=v"(r) : "v"(a), "v"(b));
  return r;
}
__device__ __forceinline__ float lo16f(unsigned v){ return __uint_as_float(v << 16); }
__device__ __forceinline__ float hi16f(unsigned v){ return __uint_as_float(v & 0xFFFF0000u); }
__device__ __forceinline__ void split8(const float* s, bf16x8& hi, bf16x8& lo){
  #pragma unroll
  for (int e=0;e<8;e++){
    unsigned short hb = bf16_rne(s[e]);
    float lof = s[e] - __uint_as_float(((unsigned)hb)<<16);
    hi[e] = (short)hb; lo[e] = (short)bf16_rne(lof);
  }
}
__device__ __forceinline__ void accum8(float* a, uint4 v){
  unsigned x[4] = {v.x, v.y, v.z, v.w};
  #pragma unroll
  for (int q=0;q<4;q++){
    a[2*q]   += __uint_as_float((x[q]&0xFFFFu)<<16);
    a[2*q+1] += __uint_as_float(x[q]&0xFFFF0000u);
  }
}

// ---------------- path embedding ----------------
__global__ __launch_bounds__(256) void path_embed(
    const float* __restrict__ ft, const float* __restrict__ fp, const float* __restrict__ fps,
    const float* __restrict__ w1, const float* __restrict__ b1,
    const float* __restrict__ w2, const float* __restrict__ b2,
    float* __restrict__ path_state)
{
  __shared__ float h1[4][DIM];
  int j  = threadIdx.x & 63;
  int pl = threadIdx.x >> 6;
  int p  = blockIdx.x*4 + pl;
  float x0 = ft[p]*1e-4f, x1 = fp[p]*1e-3f, x2 = fps[p]*1e-3f;
  float h = b1[j] + x0*w1[0*DIM+j] + x1*w1[1*DIM+j] + x2*w1[2*DIM+j];
  h1[pl][j] = fmaxf(h, 0.f);
  __syncthreads();
  float acc = b2[j];
  #pragma unroll 8
  for (int k=0;k<DIM;k++) acc = fmaf(h1[pl][k], w2[k*DIM+j], acc);
  path_state[p*DIM+j] = fmaxf(acc, 0.f);
}

// ---------------- link embedding ----------------
__global__ __launch_bounds__(256) void link_embed(
    const float* __restrict__ ft, const float* __restrict__ cap, const int* __restrict__ ptl,
    const float* __restrict__ w1, const float* __restrict__ b1,
    const float* __restrict__ w2, const float* __restrict__ b2,
    float* __restrict__ link_state)
{
  __shared__ float h1[4][DIM];
  int j  = threadIdx.x & 63;
  int wl = threadIdx.x >> 6;
  int l  = blockIdx.x*4 + wl;
  float s = 0.f;
  if (j < DEG) s = ft[ptl[(l*DEG + j)*2 + 0]];
  #pragma unroll
  for (int off=32; off; off>>=1) s += __shfl_down(s, off);
  float load = __shfl(s, 0) / (cap[l]*1e9f);
  float x0 = cap[l]*1e-5f;
  float h = b1[j] + x0*w1[0*DIM+j] + load*w1[1*DIM+j];
  h1[wl][j] = fmaxf(h, 0.f);
  __syncthreads();
  float acc = b2[j];
  #pragma unroll 8
  for (int k=0;k<DIM;k++) acc = fmaf(h1[wl][k], w2[k*DIM+j], acc);
  link_state[l*DIM+j] = fmaxf(acc, 0.f);
}

// ---------------- pack 4 weight mats into bf16 MFMA fragments ----------------
__global__ __launch_bounds__(256) void pack_frags(
    const float* __restrict__ pg_wh, const float* __restrict__ pg_wx,
    const float* __restrict__ lg_wx, const float* __restrict__ lg_wh,
    unsigned short* __restrict__ whf)
{
  int tid = blockIdx.x*256 + threadIdx.x;
  if (tid >= 4*24*512) return;
  int i = tid & 7, l = (tid>>3)&63, f = (tid>>9)%24, m = tid/(24*512);
  int nt = f>>1, kc = f&1;
  int k = kc*32 + (l>>4)*8 + i;
  int n = nt*16 + (l&15);
  const float* src = (m==0)?pg_wh : (m==1)?pg_wx : (m==2)?lg_wx : lg_wh;
  whf[tid] = bf16_rne(src[k*G3 + n]);
}

// ---------------- initial LX, packed bf16 [dim][z,r,q], 384 B/link ----------------
__global__ __launch_bounds__(192) void compute_lx(
    const float* __restrict__ link_state, const float* __restrict__ wx,
    const float* __restrict__ bx, const float* __restrict__ bh,
    unsigned short* __restrict__ LXq)
{
  __shared__ float ls[4][DIM];
  int g  = threadIdx.x;
  int l0 = blockIdx.x*4;
  if (g < DIM){
    #pragma unroll
    for (int li=0; li<4; li++) ls[li][g] = link_state[(l0+li)*DIM+g];
  }
  __syncthreads();
  float b = bx[g] + (g < 128 ? bh[g] : 0.f);
  float a0=b, a1=b, a2=b, a3=b;
  #pragma unroll 8
  for (int k=0;k<DIM;k++){
    float w = wx[k*G3+g];
    a0 = fmaf(ls[0][k], w, a0);
    a1 = fmaf(ls[1][k], w, a1);
    a2 = fmaf(ls[2][k], w, a2);
    a3 = fmaf(ls[3][k], w, a3);
  }
  int comp = g >> 6, dim = g & 63;
  int pos = dim*3 + comp;
  LXq[(size_t)(l0+0)*G3+pos]=bf16_rne(a0);
  LXq[(size_t)(l0+1)*G3+pos]=bf16_rne(a1);
  LXq[(size_t)(l0+2)*G3+pos]=bf16_rne(a2);
  LXq[(size_t)(l0+3)*G3+pos]=bf16_rne(a3);
}

// ---------------- MFMA 8-step GRU scan: transposed-D n-split + LX prefetch (r10 base) ----------------
__global__ __launch_bounds__(256) void path_scan_mfma(
    const unsigned short* __restrict__ LXq, const int* __restrict__ ltp,
    const unsigned short* __restrict__ whf, const float* __restrict__ bh,
    float* __restrict__ path_state, unsigned short* __restrict__ seq16)
{
  __shared__ __align__(16) unsigned short htile[2][16*72];  // [buf][path][dim], pitch 72
  __shared__ int ltps[128];
  int tid = threadIdx.x, l = tid & 63, w = tid >> 6;
  int lg = l >> 4, lr = l & 15;
  int p0 = blockIdx.x*16;                 // 50000/16 = 3125 exact

  bf16x8 bf[3][2];
  #pragma unroll
  for (int j=0;j<3;j++){
    int nt = w + j*4;
    bf[j][0] = *(const bf16x8*)(whf + (size_t)(nt*2+0)*512 + l*8);
    bf[j][1] = *(const bf16x8*)(whf + (size_t)(nt*2+1)*512 + l*8);
  }
  float bhq[4];
  #pragma unroll
  for (int r=0;r<4;r++) bhq[r] = bh[128 + w*16 + lg*4 + r];

  if (tid < 128) ltps[tid] = ltp[(size_t)p0*LPATH + tid];

  {
    int pi = tid >> 4, c4 = (tid & 15)*4;
    float4 v = *(const float4*)(path_state + (size_t)(p0+pi)*DIM + c4);
    uint2 u = make_uint2(pack_bf16(v.x, v.y), pack_bf16(v.z, v.w));
    *(uint2*)&htile[0][pi*72 + c4] = u;
  }
  f32x4 hold = *(const f32x4*)(path_state + (size_t)(p0+lr)*DIM + w*16 + lg*4);

  __syncthreads();

  unsigned short* seqp = seq16 + ((size_t)(p0+lr)*LPATH)*DIM + w*16 + lg*4;
  const size_t dimoff = (size_t)(w*16 + lg*4)*3;
  int cur = 0;

  uint2 c0, c1, c2;
  {
    const unsigned short* x = LXq + (size_t)ltps[lr*LPATH]*G3 + dimoff;
    c0 = *(const uint2*)x; c1 = *(const uint2*)(x+4); c2 = *(const uint2*)(x+8);
  }

  for (int t=0; t<LPATH; t++){
    // 1) issue NEXT step's LX gather (full step to land; L2-resident 3.84MB array)
    int tn = (t < LPATH-1) ? t+1 : t;
    const unsigned short* xn = LXq + (size_t)ltps[lr*LPATH + tn]*G3 + dimoff;
    uint2 n0 = *(const uint2*)xn, n1 = *(const uint2*)(xn+4), n2 = *(const uint2*)(xn+8);

    // 2) h fragments + 6 MFMAs (depend only on LDS)
    bf16x8 h0 = *(const bf16x8*)&htile[cur][lr*72 +  0 + lg*8];
    bf16x8 h1 = *(const bf16x8*)&htile[cur][lr*72 + 32 + lg*8];
    f32x4 accz = (f32x4){0.f,0.f,0.f,0.f};
    f32x4 accr = (f32x4){0.f,0.f,0.f,0.f};
    f32x4 accq = (f32x4){bhq[0],bhq[1],bhq[2],bhq[3]};
    accz = __builtin_amdgcn_mfma_f32_16x16x32_bf16(bf[0][0], h0, accz, 0,0,0);
    accr = __builtin_amdgcn_mfma_f32_16x16x32_bf16(bf[1][0], h0, accr, 0,0,0);
    accq = __builtin_amdgcn_mfma_f32_16x16x32_bf16(bf[2][0], h0, accq, 0,0,0);
    accz = __builtin_amdgcn_mfma_f32_16x16x32_bf16(bf[0][1], h1, accz, 0,0,0);
    accr = __builtin_amdgcn_mfma_f32_16x16x32_bf16(bf[1][1], h1, accr, 0,0,0);
    accq = __builtin_amdgcn_mfma_f32_16x16x32_bf16(bf[2][1], h1, accq, 0,0,0);

    // 3) gates consume CURRENT prefetched LX regs
    float lz[4]  = { lo16f(c0.x), hi16f(c0.y), lo16f(c1.y), hi16f(c2.x) };
    float lrr[4] = { hi16f(c0.x), lo16f(c1.x), hi16f(c1.y), lo16f(c2.y) };
    float lq[4]  = { lo16f(c0.y), hi16f(c1.x), lo16f(c2.x), hi16f(c2.y) };
    f32x4 hn;
    #pragma unroll
    for (int r=0;r<4;r++){
      float z  = fsigmoid(lz[r]  + accz[r]);
      float rr = fsigmoid(lrr[r] + accr[r]);
      float hh = ftanh(lq[r] + rr*accq[r]);
      hn[r] = fmaf(z, hold[r]-hh, hh);   // z*h + (1-z)*q, 2 ops
    }
    hold = hn;
    uint2 u = make_uint2(pack_bf16(hn[0], hn[1]), pack_bf16(hn[2], hn[3]));
    *(uint2*)&htile[cur^1][lr*72 + w*16 + lg*4] = u;
    *(uint2*)(seqp + (size_t)t*DIM) = u;
    __syncthreads();
    cur ^= 1;
    c0 = n0; c1 = n1; c2 = n2;
  }
  *(f32x4*)(path_state + (size_t)(p0+lr)*DIM + w*16 + lg*4) = hold;
}

// ---------------- fused link update: 4-wave parallel GRU + next LX ----------------
__global__ __launch_bounds__(256) void link_fused(
    const unsigned short* __restrict__ seq16, const int* __restrict__ ptl,
    const unsigned short* __restrict__ whf,
    const float* __restrict__ lbx, const float* __restrict__ lbh,
    const float* __restrict__ pbx, const float* __restrict__ pbh,
    float* __restrict__ link_state, unsigned short* __restrict__ LXq)
{
  __shared__ float pspart[4][16][64];
  __shared__ float tile[16*68];
  int tid = threadIdx.x, l = tid & 63, w = tid >> 6;
  int lr = l & 15, lg = l >> 4;
  int l0 = blockIdx.x*16;

  float ps[16];
  #pragma unroll
  for (int i=0;i<16;i++) ps[i]=0.f;
  {
    const int* pe = ptl + (size_t)(l0+lr)*DEG*2 + w*10*2;
    #pragma unroll
    for (int d=0; d<10; d++){
      int pp = pe[2*d], tt = pe[2*d+1];
      const unsigned short* rowp = seq16 + ((size_t)pp*LPATH + (tt-1))*DIM;
      accum8(ps,   *(const uint4*)(rowp + lg*8));
      accum8(ps+8, *(const uint4*)(rowp + 32 + lg*8));
    }
  }
  #pragma unroll
  for (int i=0;i<16;i++) pspart[w][i][l] = ps[i];
  __syncthreads();

  #pragma unroll
  for (int i=0;i<16;i++)
    ps[i] = pspart[0][i][l] + pspart[1][i][l] + pspart[2][i][l] + pspart[3][i][l];

  bf16x8 phi[2], plo[2], lhi[2], llo[2];
  #pragma unroll
  for (int kc=0;kc<2;kc++){
    split8(ps + kc*8, phi[kc], plo[kc]);
    float hs[8];
    const float* lsr = link_state + (size_t)(l0+lr)*DIM + kc*32 + lg*8;
    *(f32x4*)hs = *(const f32x4*)lsr;
    *(f32x4*)(hs+4) = *(const f32x4*)(lsr+4);
    split8(hs, lhi[kc], llo[kc]);
  }
  f32x4 mxa[3], mha[3];
  #pragma unroll
  for (int j=0;j<3;j++){
    int nt = w + j*4;
    float bxv = lbx[nt*16+lr], bhv = lbh[nt*16+lr];
    mxa[j] = (f32x4){bxv,bxv,bxv,bxv};
    mha[j] = (f32x4){bhv,bhv,bhv,bhv};
    #pragma unroll
    for (int kc=0;kc<2;kc++){
      bf16x8 bwx = *(const bf16x8*)(whf + (size_t)((2*24 + nt*2+kc)*512) + l*8);
      mxa[j] = __builtin_amdgcn_mfma_f32_16x16x32_bf16(phi[kc], bwx, mxa[j], 0,0,0);
      mxa[j] = __builtin_amdgcn_mfma_f32_16x16x32_bf16(plo[kc], bwx, mxa[j], 0,0,0);
      bf16x8 bwh = *(const bf16x8*)(whf + (size_t)((3*24 + nt*2+kc)*512) + l*8);
      mha[j] = __builtin_amdgcn_mfma_f32_16x16x32_bf16(lhi[kc], bwh, mha[j], 0,0,0);
      mha[j] = __builtin_amdgcn_mfma_f32_16x16x32_bf16(llo[kc], bwh, mha[j], 0,0,0);
    }
  }
  __syncthreads();

  #pragma unroll
  for (int r=0;r<4;r++){
    size_t lk = (size_t)(l0 + lg*4 + r)*DIM + w*16 + lr;
    float lsv = link_state[lk];
    float z  = fsigmoid(mxa[0][r] + mha[0][r]);
    float rr = fsigmoid(mxa[1][r] + mha[1][r]);
    float hh = ftanh(mxa[2][r] + rr*mha[2][r]);
    float hn = fmaf(z, lsv-hh, hh);
    link_state[lk] = hn;
    tile[(lg*4+r)*68 + w*16 + lr] = hn;
  }
  __syncthreads();

  f32x4 lxa[3];
  #pragma unroll
  for (int j=0;j<3;j++){
    int g = (w + j*4)*16 + lr;
    float b = pbx[g] + (g < 128 ? pbh[g] : 0.f);
    lxa[j] = (f32x4){b,b,b,b};
  }
  #pragma unroll
  for (int kc=0;kc<2;kc++){
    float hs[8];
    #pragma unroll
    for (int i=0;i<8;i++) hs[i] = tile[lr*68 + kc*32 + lg*8 + i];
    bf16x8 thi, tlo; split8(hs, thi, tlo);
    #pragma unroll
    for (int j=0;j<3;j++){
      int nt = w + j*4;
      bf16x8 bw = *(const bf16x8*)(whf + (size_t)((1*24 + nt*2+kc)*512) + l*8);
      lxa[j] = __builtin_amdgcn_mfma_f32_16x16x32_bf16(thi, bw, lxa[j], 0,0,0);
      lxa[j] = __builtin_amdgcn_mfma_f32_16x16x32_bf16(tlo, bw, lxa[j], 0,0,0);
    }
  }
  #pragma unroll
  for (int r=0;r<4;r++){
    int link = l0 + lg*4 + r;
    size_t base = (size_t)link*G3 + (size_t)(w*16 + lr)*3;
    LXq[base+0] = bf16_rne(lxa[0][r]);
    LXq[base+1] = bf16_rne(lxa[1][r]);
    LXq[base+2] = bf16_rne(lxa[2][r]);
  }
}

// ---------------- readout: LDS-staged coalesced reads (r10 known-good) ----------------
__global__ __launch_bounds__(256) void readout(
    const unsigned short* __restrict__ seq16, const int* __restrict__ ltp,
    const float* __restrict__ cap,
    const float* __restrict__ w1, const float* __restrict__ b1,
    const float* __restrict__ w2, const float* __restrict__ b2,
    const float* __restrict__ w3, const float* __restrict__ b3,
    float* __restrict__ out)
{
  __shared__ unsigned short rows_sh[4][64*72];
  __shared__ float w1s[DIM*32];
  __shared__ float w2s[32*16];
  __shared__ float w3s[16];
  __shared__ float b1s[32], b2s[16];
  int tid = threadIdx.x;
  for (int i=tid;i<DIM*32;i+=256) w1s[i]=w1[i];
  for (int i=tid;i<32*16;i+=256) w2s[i]=w2[i];
  if (tid<16) w3s[tid]=w3[tid];
  if (tid<32) b1s[tid]=b1[tid];
  if (tid<16) b2s[tid]=b2[tid];
  __syncthreads();

  int l = tid & 63, w = tid >> 6;
  size_t wave_r = (size_t)blockIdx.x*256 + (size_t)w*64;
  if (wave_r >= (size_t)N_PATHS*LPATH) return;

  const unsigned short* src = seq16 + wave_r*DIM;
  #pragma unroll
  for (int i=0;i<16;i++){
    int e  = i*64 + l;
    int ri = e >> 4;
    int c4 = e & 15;
    *(uint2*)&rows_sh[w][ri*72 + c4*4] = *(const uint2*)(src + (size_t)e*4);
  }

  size_t row = wave_r + l;
  const unsigned short* myrow = &rows_sh[w][l*72];
  float a[32];
  #pragma unroll
  for (int j=0;j<32;j++) a[j]=b1s[j];
  #pragma unroll
  for (int c=0;c<16;c++){
    uint2 v = *(const uint2*)(myrow + c*4);
    float f0 = __uint_as_float((v.x & 0xFFFFu) << 16);
    float f1 = __uint_as_float(v.x & 0xFFFF0000u);
    float f2 = __uint_as_float((v.y & 0xFFFFu) << 16);
    float f3 = __uint_as_float(v.y & 0xFFFF0000u);
    #pragma unroll
    for (int j=0;j<32;j++) a[j] = fmaf(f0, w1s[(c*4+0)*32+j], a[j]);
    #pragma unroll
    for (int j=0;j<32;j++) a[j] = fmaf(f1, w1s[(c*4+1)*32+j], a[j]);
    #pragma unroll
    for (int j=0;j<32;j++) a[j] = fmaf(f2, w1s[(c*4+2)*32+j], a[j]);
    #pragma unroll
    for (int j=0;j<32;j++) a[j] = fmaf(f3, w1s[(c*4+3)*32+j], a[j]);
  }
  float h2[16];
  #pragma unroll
  for (int j2=0;j2<16;j2++) h2[j2]=b2s[j2];
  #pragma unroll
  for (int j=0;j<32;j++){
    float hv = fmaxf(a[j],0.f);
    #pragma unroll
    for (int j2=0;j2<16;j2++) h2[j2] = fmaf(hv, w2s[j*16+j2], h2[j2]);
  }
  float o = b3[0];
  #pragma unroll
  for (int j2=0;j2<16;j2++) o = fmaf(fmaxf(h2[j2],0.f), w3s[j2], o);
  float sp = (o > 20.f) ? o : log1pf(__expf(o));
  float dly = sp / cap[ltp[row]];
  dly += __shfl_xor(dly, 1);
  dly += __shfl_xor(dly, 2);
  dly += __shfl_xor(dly, 4);
  if ((l & 7) == 0) out[row >> 3] = dly;
}

extern "C" void kernel_launch(void* const* d_in, const int* in_sizes, int n_in,
                              void* d_out, int out_size, void* d_ws, size_t ws_size,
                              hipStream_t stream) {
  const float* ft    = (const float*)d_in[0];
  const float* fpk   = (const float*)d_in[1];
  const float* fps   = (const float*)d_in[2];
  const float* cap   = (const float*)d_in[3];
  const int*   ltp   = (const int*)  d_in[4];
  const int*   ptl   = (const int*)  d_in[5];
  const float* pe_w1 = (const float*)d_in[6];
  const float* pe_b1 = (const float*)d_in[7];
  const float* pe_w2 = (const float*)d_in[8];
  const float* pe_b2 = (const float*)d_in[9];
  const float* le_w1 = (const float*)d_in[10];
  const float* le_b1 = (const float*)d_in[11];
  const float* le_w2 = (const float*)d_in[12];
  const float* le_b2 = (const float*)d_in[13];
  const float* pg_wx = (const float*)d_in[14];
  const float* pg_wh = (const float*)d_in[15];
  const float* pg_bx = (const float*)d_in[16];
  const float* pg_bh = (const float*)d_in[17];
  const float* lg_wx = (const float*)d_in[18];
  const float* lg_wh = (const float*)d_in[19];
  const float* lg_bx = (const float*)d_in[20];
  const float* lg_bh = (const float*)d_in[21];
  const float* ro_w1 = (const float*)d_in[22];
  const float* ro_b1 = (const float*)d_in[23];
  const float* ro_w2 = (const float*)d_in[24];
  const float* ro_b2 = (const float*)d_in[25];
  const float* ro_w3 = (const float*)d_in[26];
  const float* ro_b3 = (const float*)d_in[27];
  float* out = (float*)d_out;

  float* path_state = (float*)d_ws;
  float* link_state = path_state + (size_t)N_PATHS*DIM;
  unsigned short* LXq   = (unsigned short*)(link_state + (size_t)N_LINKS*DIM);  // 10000*192
  unsigned short* seq16 = LXq + (size_t)N_LINKS*G3;
  unsigned short* whf   = seq16 + (size_t)N_PATHS*LPATH*DIM;

  path_embed<<<N_PATHS/4, 256, 0, stream>>>(ft, fpk, fps, pe_w1, pe_b1, pe_w2, pe_b2, path_state);
  link_embed<<<N_LINKS/4, 256, 0, stream>>>(ft, cap, ptl, le_w1, le_b1, le_w2, le_b2, link_state);
  pack_frags<<<192, 256, 0, stream>>>(pg_wh, pg_wx, lg_wx, lg_wh, whf);
  compute_lx<<<N_LINKS/4, 192, 0, stream>>>(link_state, pg_wx, pg_bx, pg_bh, LXq);
  for (int it=0; it<ITERS; ++it){
    path_scan_mfma<<<N_PATHS/16, 256, 0, stream>>>(LXq, ltp, whf, pg_bh, path_state, seq16);
    if (it < ITERS-1)
      link_fused<<<N_LINKS/16, 256, 0, stream>>>(seq16, ptl, whf,
          lg_bx, lg_bh, pg_bx, pg_bh, link_state, LXq);
  }
  readout<<<(N_PATHS*LPATH + 255)/256, 256, 0, stream>>>(seq16, ltp, cap,
      ro_w1, ro_b1, ro_w2, ro_b2, ro_w3, ro_b3, out);
}

// Round 15
// 522.486 us; speedup vs baseline: 1.7328x; 1.0388x over previous
//
#include <hip/hip_runtime.h>
#include <math.h>

#define N_PATHS 50000
#define N_LINKS 10000
#define LPATH   8
#define DEG     40
#define DIM     64
#define G3      192
#define ITERS   8
#define ROF_OFF (4*24*512)   // ushort offset of readout weight frags in whf

typedef float f32x4  __attribute__((ext_vector_type(4)));
typedef short bf16x8 __attribute__((ext_vector_type(8)));

// fast gates: raw v_rcp_f32 (~1 ulp) instead of IEEE div (~10 VALU ops each)
__device__ __forceinline__ float fsigmoid(float x){
  return __builtin_amdgcn_rcpf(1.0f + __expf(-x));
}
__device__ __forceinline__ float ftanh(float x){
  return 1.0f - 2.0f*__builtin_amdgcn_rcpf(__expf(2.0f*x) + 1.0f);
}
__device__ __forceinline__ unsigned short bf16_rne(float v){
  unsigned u = __float_as_uint(v);
  return (unsigned short)((u + 0x7FFFu + ((u>>16)&1u)) >> 16);
}
__device__ __forceinline__ unsigned pack_bf16(float a, float b){
  unsigned r;
  asm("v_cvt_pk_bf16_f32 %0, %1, %2" : "=v"(r) : "v"(a), "v"(b));
  return r;
}
__device__ __forceinline__ float lo16f(unsigned v){ return __uint_as_float(v << 16); }
__device__ __forceinline__ float hi16f(unsigned v){ return __uint_as_float(v & 0xFFFF0000u); }
__device__ __forceinline__ void split8(const float* s, bf16x8& hi, bf16x8& lo){
  #pragma unroll
  for (int e=0;e<8;e++){
    unsigned short hb = bf16_rne(s[e]);
    float lof = s[e] - __uint_as_float(((unsigned)hb)<<16);
    hi[e] = (short)hb; lo[e] = (short)bf16_rne(lof);
  }
}
__device__ __forceinline__ void accum8(float* a, uint4 v){
  unsigned x[4] = {v.x, v.y, v.z, v.w};
  #pragma unroll
  for (int q=0;q<4;q++){
    a[2*q]   += __uint_as_float((x[q]&0xFFFFu)<<16);
    a[2*q+1] += __uint_as_float(x[q]&0xFFFF0000u);
  }
}

// ---------------- path embedding ----------------
__global__ __launch_bounds__(256) void path_embed(
    const float* __restrict__ ft, const float* __restrict__ fp, const float* __restrict__ fps,
    const float* __restrict__ w1, const float* __restrict__ b1,
    const float* __restrict__ w2, const float* __restrict__ b2,
    float* __restrict__ path_state)
{
  __shared__ float h1[4][DIM];
  int j  = threadIdx.x & 63;
  int pl = threadIdx.x >> 6;
  int p  = blockIdx.x*4 + pl;
  float x0 = ft[p]*1e-4f, x1 = fp[p]*1e-3f, x2 = fps[p]*1e-3f;
  float h = b1[j] + x0*w1[0*DIM+j] + x1*w1[1*DIM+j] + x2*w1[2*DIM+j];
  h1[pl][j] = fmaxf(h, 0.f);
  __syncthreads();
  float acc = b2[j];
  #pragma unroll 8
  for (int k=0;k<DIM;k++) acc = fmaf(h1[pl][k], w2[k*DIM+j], acc);
  path_state[p*DIM+j] = fmaxf(acc, 0.f);
}

// ---------------- link embedding ----------------
__global__ __launch_bounds__(256) void link_embed(
    const float* __restrict__ ft, const float* __restrict__ cap, const int* __restrict__ ptl,
    const float* __restrict__ w1, const float* __restrict__ b1,
    const float* __restrict__ w2, const float* __restrict__ b2,
    float* __restrict__ link_state)
{
  __shared__ float h1[4][DIM];
  int j  = threadIdx.x & 63;
  int wl = threadIdx.x >> 6;
  int l  = blockIdx.x*4 + wl;
  float s = 0.f;
  if (j < DEG) s = ft[ptl[(l*DEG + j)*2 + 0]];
  #pragma unroll
  for (int off=32; off; off>>=1) s += __shfl_down(s, off);
  float load = __shfl(s, 0) / (cap[l]*1e9f);
  float x0 = cap[l]*1e-5f;
  float h = b1[j] + x0*w1[0*DIM+j] + load*w1[1*DIM+j];
  h1[wl][j] = fmaxf(h, 0.f);
  __syncthreads();
  float acc = b2[j];
  #pragma unroll 8
  for (int k=0;k<DIM;k++) acc = fmaf(h1[wl][k], w2[k*DIM+j], acc);
  link_state[l*DIM+j] = fmaxf(acc, 0.f);
}

// ---------------- pack weight mats into bf16 MFMA fragments ----------------
// m<4: pg_wh,pg_wx,lg_wx,lg_wh (24 frags each). Then ro_w1 (4 frags), ro_w2 (1 frag).
__global__ __launch_bounds__(256) void pack_frags(
    const float* __restrict__ pg_wh, const float* __restrict__ pg_wx,
    const float* __restrict__ lg_wx, const float* __restrict__ lg_wh,
    const float* __restrict__ ro_w1, const float* __restrict__ ro_w2,
    unsigned short* __restrict__ whf)
{
  int tid = blockIdx.x*256 + threadIdx.x;
  int i = tid & 7, l = (tid>>3)&63;
  if (tid < ROF_OFF){
    int f = (tid>>9)%24, m = tid/(24*512);
    int nt = f>>1, kc = f&1;
    int k = kc*32 + (l>>4)*8 + i;
    int n = nt*16 + (l&15);
    const float* src = (m==0)?pg_wh : (m==1)?pg_wx : (m==2)?lg_wx : lg_wh;
    whf[tid] = bf16_rne(src[k*G3 + n]);
  } else if (tid < ROF_OFF + 4*512){
    int f = (tid - ROF_OFF) >> 9;         // 0..3
    int nt = f>>1, kc = f&1;
    whf[tid] = bf16_rne(ro_w1[(kc*32 + (l>>4)*8 + i)*32 + nt*16 + (l&15)]);
  } else if (tid < ROF_OFF + 5*512){
    whf[tid] = bf16_rne(ro_w2[((l>>4)*8 + i)*16 + (l&15)]);
  }
}

// ---------------- initial LX, packed bf16 [dim][z,r,q], 384 B/link ----------------
__global__ __launch_bounds__(192) void compute_lx(
    const float* __restrict__ link_state, const float* __restrict__ wx,
    const float* __restrict__ bx, const float* __restrict__ bh,
    unsigned short* __restrict__ LXq)
{
  __shared__ float ls[4][DIM];
  int g  = threadIdx.x;
  int l0 = blockIdx.x*4;
  if (g < DIM){
    #pragma unroll
    for (int li=0; li<4; li++) ls[li][g] = link_state[(l0+li)*DIM+g];
  }
  __syncthreads();
  float b = bx[g] + (g < 128 ? bh[g] : 0.f);
  float a0=b, a1=b, a2=b, a3=b;
  #pragma unroll 8
  for (int k=0;k<DIM;k++){
    float w = wx[k*G3+g];
    a0 = fmaf(ls[0][k], w, a0);
    a1 = fmaf(ls[1][k], w, a1);
    a2 = fmaf(ls[2][k], w, a2);
    a3 = fmaf(ls[3][k], w, a3);
  }
  int comp = g >> 6, dim = g & 63;
  int pos = dim*3 + comp;
  LXq[(size_t)(l0+0)*G3+pos]=bf16_rne(a0);
  LXq[(size_t)(l0+1)*G3+pos]=bf16_rne(a1);
  LXq[(size_t)(l0+2)*G3+pos]=bf16_rne(a2);
  LXq[(size_t)(l0+3)*G3+pos]=bf16_rne(a3);
}

// ---------------- MFMA 8-step GRU scan (r14, unchanged) ----------------
__global__ __launch_bounds__(256) void path_scan_mfma(
    const unsigned short* __restrict__ LXq, const int* __restrict__ ltp,
    const unsigned short* __restrict__ whf, const float* __restrict__ bh,
    float* __restrict__ path_state, unsigned short* __restrict__ seq16)
{
  __shared__ __align__(16) unsigned short htile[2][16*72];
  __shared__ int ltps[128];
  int tid = threadIdx.x, l = tid & 63, w = tid >> 6;
  int lg = l >> 4, lr = l & 15;
  int p0 = blockIdx.x*16;

  bf16x8 bf[3][2];
  #pragma unroll
  for (int j=0;j<3;j++){
    int nt = w + j*4;
    bf[j][0] = *(const bf16x8*)(whf + (size_t)(nt*2+0)*512 + l*8);
    bf[j][1] = *(const bf16x8*)(whf + (size_t)(nt*2+1)*512 + l*8);
  }
  float bhq[4];
  #pragma unroll
  for (int r=0;r<4;r++) bhq[r] = bh[128 + w*16 + lg*4 + r];

  if (tid < 128) ltps[tid] = ltp[(size_t)p0*LPATH + tid];

  {
    int pi = tid >> 4, c4 = (tid & 15)*4;
    float4 v = *(const float4*)(path_state + (size_t)(p0+pi)*DIM + c4);
    uint2 u = make_uint2(pack_bf16(v.x, v.y), pack_bf16(v.z, v.w));
    *(uint2*)&htile[0][pi*72 + c4] = u;
  }
  f32x4 hold = *(const f32x4*)(path_state + (size_t)(p0+lr)*DIM + w*16 + lg*4);

  __syncthreads();

  unsigned short* seqp = seq16 + ((size_t)(p0+lr)*LPATH)*DIM + w*16 + lg*4;
  const size_t dimoff = (size_t)(w*16 + lg*4)*3;
  int cur = 0;

  uint2 c0, c1, c2;
  {
    const unsigned short* x = LXq + (size_t)ltps[lr*LPATH]*G3 + dimoff;
    c0 = *(const uint2*)x; c1 = *(const uint2*)(x+4); c2 = *(const uint2*)(x+8);
  }

  for (int t=0; t<LPATH; t++){
    int tn = (t < LPATH-1) ? t+1 : t;
    const unsigned short* xn = LXq + (size_t)ltps[lr*LPATH + tn]*G3 + dimoff;
    uint2 n0 = *(const uint2*)xn, n1 = *(const uint2*)(xn+4), n2 = *(const uint2*)(xn+8);

    bf16x8 h0 = *(const bf16x8*)&htile[cur][lr*72 +  0 + lg*8];
    bf16x8 h1 = *(const bf16x8*)&htile[cur][lr*72 + 32 + lg*8];
    f32x4 accz = (f32x4){0.f,0.f,0.f,0.f};
    f32x4 accr = (f32x4){0.f,0.f,0.f,0.f};
    f32x4 accq = (f32x4){bhq[0],bhq[1],bhq[2],bhq[3]};
    accz = __builtin_amdgcn_mfma_f32_16x16x32_bf16(bf[0][0], h0, accz, 0,0,0);
    accr = __builtin_amdgcn_mfma_f32_16x16x32_bf16(bf[1][0], h0, accr, 0,0,0);
    accq = __builtin_amdgcn_mfma_f32_16x16x32_bf16(bf[2][0], h0, accq, 0,0,0);
    accz = __builtin_amdgcn_mfma_f32_16x16x32_bf16(bf[0][1], h1, accz, 0,0,0);
    accr = __builtin_amdgcn_mfma_f32_16x16x32_bf16(bf[1][1], h1, accr, 0,0,0);
    accq = __builtin_amdgcn_mfma_f32_16x16x32_bf16(bf[2][1], h1, accq, 0,0,0);

    float lz[4]  = { lo16f(c0.x), hi16f(c0.y), lo16f(c1.y), hi16f(c2.x) };
    float lrr[4] = { hi16f(c0.x), lo16f(c1.x), hi16f(c1.y), lo16f(c2.y) };
    float lq[4]  = { lo16f(c0.y), hi16f(c1.x), lo16f(c2.x), hi16f(c2.y) };
    f32x4 hn;
    #pragma unroll
    for (int r=0;r<4;r++){
      float z  = fsigmoid(lz[r]  + accz[r]);
      float rr = fsigmoid(lrr[r] + accr[r]);
      float hh = ftanh(lq[r] + rr*accq[r]);
      hn[r] = fmaf(z, hold[r]-hh, hh);
    }
    hold = hn;
    uint2 u = make_uint2(pack_bf16(hn[0], hn[1]), pack_bf16(hn[2], hn[3]));
    *(uint2*)&htile[cur^1][lr*72 + w*16 + lg*4] = u;
    *(uint2*)(seqp + (size_t)t*DIM) = u;
    __syncthreads();
    cur ^= 1;
    c0 = n0; c1 = n1; c2 = n2;
  }
  *(f32x4*)(path_state + (size_t)(p0+lr)*DIM + w*16 + lg*4) = hold;
}

// ---------------- fused link update (r14, unchanged) ----------------
__global__ __launch_bounds__(256) void link_fused(
    const unsigned short* __restrict__ seq16, const int* __restrict__ ptl,
    const unsigned short* __restrict__ whf,
    const float* __restrict__ lbx, const float* __restrict__ lbh,
    const float* __restrict__ pbx, const float* __restrict__ pbh,
    float* __restrict__ link_state, unsigned short* __restrict__ LXq)
{
  __shared__ float pspart[4][16][64];
  __shared__ float tile[16*68];
  int tid = threadIdx.x, l = tid & 63, w = tid >> 6;
  int lr = l & 15, lg = l >> 4;
  int l0 = blockIdx.x*16;

  float ps[16];
  #pragma unroll
  for (int i=0;i<16;i++) ps[i]=0.f;
  {
    const int* pe = ptl + (size_t)(l0+lr)*DEG*2 + w*10*2;
    #pragma unroll
    for (int d=0; d<10; d++){
      int pp = pe[2*d], tt = pe[2*d+1];
      const unsigned short* rowp = seq16 + ((size_t)pp*LPATH + (tt-1))*DIM;
      accum8(ps,   *(const uint4*)(rowp + lg*8));
      accum8(ps+8, *(const uint4*)(rowp + 32 + lg*8));
    }
  }
  #pragma unroll
  for (int i=0;i<16;i++) pspart[w][i][l] = ps[i];
  __syncthreads();

  #pragma unroll
  for (int i=0;i<16;i++)
    ps[i] = pspart[0][i][l] + pspart[1][i][l] + pspart[2][i][l] + pspart[3][i][l];

  bf16x8 phi[2], plo[2], lhi[2], llo[2];
  #pragma unroll
  for (int kc=0;kc<2;kc++){
    split8(ps + kc*8, phi[kc], plo[kc]);
    float hs[8];
    const float* lsr = link_state + (size_t)(l0+lr)*DIM + kc*32 + lg*8;
    *(f32x4*)hs = *(const f32x4*)lsr;
    *(f32x4*)(hs+4) = *(const f32x4*)(lsr+4);
    split8(hs, lhi[kc], llo[kc]);
  }
  f32x4 mxa[3], mha[3];
  #pragma unroll
  for (int j=0;j<3;j++){
    int nt = w + j*4;
    float bxv = lbx[nt*16+lr], bhv = lbh[nt*16+lr];
    mxa[j] = (f32x4){bxv,bxv,bxv,bxv};
    mha[j] = (f32x4){bhv,bhv,bhv,bhv};
    #pragma unroll
    for (int kc=0;kc<2;kc++){
      bf16x8 bwx = *(const bf16x8*)(whf + (size_t)((2*24 + nt*2+kc)*512) + l*8);
      mxa[j] = __builtin_amdgcn_mfma_f32_16x16x32_bf16(phi[kc], bwx, mxa[j], 0,0,0);
      mxa[j] = __builtin_amdgcn_mfma_f32_16x16x32_bf16(plo[kc], bwx, mxa[j], 0,0,0);
      bf16x8 bwh = *(const bf16x8*)(whf + (size_t)((3*24 + nt*2+kc)*512) + l*8);
      mha[j] = __builtin_amdgcn_mfma_f32_16x16x32_bf16(lhi[kc], bwh, mha[j], 0,0,0);
      mha[j] = __builtin_amdgcn_mfma_f32_16x16x32_bf16(llo[kc], bwh, mha[j], 0,0,0);
    }
  }
  __syncthreads();

  #pragma unroll
  for (int r=0;r<4;r++){
    size_t lk = (size_t)(l0 + lg*4 + r)*DIM + w*16 + lr;
    float lsv = link_state[lk];
    float z  = fsigmoid(mxa[0][r] + mha[0][r]);
    float rr = fsigmoid(mxa[1][r] + mha[1][r]);
    float hh = ftanh(mxa[2][r] + rr*mha[2][r]);
    float hn = fmaf(z, lsv-hh, hh);
    link_state[lk] = hn;
    tile[(lg*4+r)*68 + w*16 + lr] = hn;
  }
  __syncthreads();

  f32x4 lxa[3];
  #pragma unroll
  for (int j=0;j<3;j++){
    int g = (w + j*4)*16 + lr;
    float b = pbx[g] + (g < 128 ? pbh[g] : 0.f);
    lxa[j] = (f32x4){b,b,b,b};
  }
  #pragma unroll
  for (int kc=0;kc<2;kc++){
    float hs[8];
    #pragma unroll
    for (int i=0;i<8;i++) hs[i] = tile[lr*68 + kc*32 + lg*8 + i];
    bf16x8 thi, tlo; split8(hs, thi, tlo);
    #pragma unroll
    for (int j=0;j<3;j++){
      int nt = w + j*4;
      bf16x8 bw = *(const bf16x8*)(whf + (size_t)((1*24 + nt*2+kc)*512) + l*8);
      lxa[j] = __builtin_amdgcn_mfma_f32_16x16x32_bf16(thi, bw, lxa[j], 0,0,0);
      lxa[j] = __builtin_amdgcn_mfma_f32_16x16x32_bf16(tlo, bw, lxa[j], 0,0,0);
    }
  }
  #pragma unroll
  for (int r=0;r<4;r++){
    int link = l0 + lg*4 + r;
    size_t base = (size_t)link*G3 + (size_t)(w*16 + lr)*3;
    LXq[base+0] = bf16_rne(lxa[0][r]);
    LXq[base+1] = bf16_rne(lxa[1][r]);
    LXq[base+2] = bf16_rne(lxa[2][r]);
  }
}

// ---------------- readout: MFMA MLP. wave = 64 rows (4 x 16-row tiles) ----------------
// Layer1 [16x64]@[64x32] via 4 MFMAs (A straight from seq16); relu -> bf16 -> wave-private
// LDS transpose tile; layer2 [16x32]@[32x16] via 1 MFMA; layer3 via w3 + shfl butterfly.
__global__ __launch_bounds__(256) void readout(
    const unsigned short* __restrict__ seq16, const int* __restrict__ ltp,
    const float* __restrict__ cap, const unsigned short* __restrict__ whf,
    const float* __restrict__ b1, const float* __restrict__ b2,
    const float* __restrict__ w3, const float* __restrict__ b3,
    float* __restrict__ out)
{
  __shared__ __align__(16) unsigned short tr[4][2][16*40];  // [wave][buf][row][neuron]
  int tid = threadIdx.x, l = tid & 63, w = tid >> 6;
  int lg = l >> 4, lr = l & 15;
  size_t wbase = (size_t)blockIdx.x*256 + (size_t)w*64;
  if (wbase >= (size_t)N_PATHS*LPATH) return;   // tail: waves 2,3 of last block

  const unsigned short* rof = whf + ROF_OFF;
  bf16x8 w1f[2][2], w2f;
  #pragma unroll
  for (int nt=0;nt<2;nt++)
    #pragma unroll
    for (int kc=0;kc<2;kc++)
      w1f[nt][kc] = *(const bf16x8*)(rof + (size_t)(nt*2+kc)*512 + l*8);
  w2f = *(const bf16x8*)(rof + (size_t)4*512 + l*8);
  float b1a = b1[lr], b1b = b1[16+lr], b2v = b2[lr], w3v = w3[lr], b3v = b3[0];

  // preload all 4 tiles' A fragments (rows of seq16, 16B/lane, contiguous coverage)
  bf16x8 a0[4], a1[4];
  #pragma unroll
  for (int tt=0;tt<4;tt++){
    const unsigned short* ap = seq16 + (wbase + tt*16 + lr)*DIM + lg*8;
    a0[tt] = *(const bf16x8*)ap;
    a1[tt] = *(const bf16x8*)(ap + 32);
  }

  #pragma unroll
  for (int tt=0;tt<4;tt++){
    size_t rowbase = wbase + tt*16;
    // layer 1: two n-tiles
    f32x4 acc1a = (f32x4){b1a,b1a,b1a,b1a};
    f32x4 acc1b = (f32x4){b1b,b1b,b1b,b1b};
    acc1a = __builtin_amdgcn_mfma_f32_16x16x32_bf16(a0[tt], w1f[0][0], acc1a, 0,0,0);
    acc1a = __builtin_amdgcn_mfma_f32_16x16x32_bf16(a1[tt], w1f[0][1], acc1a, 0,0,0);
    acc1b = __builtin_amdgcn_mfma_f32_16x16x32_bf16(a0[tt], w1f[1][0], acc1b, 0,0,0);
    acc1b = __builtin_amdgcn_mfma_f32_16x16x32_bf16(a1[tt], w1f[1][1], acc1b, 0,0,0);
    // relu -> bf16 -> transpose tile (D: row=(lg*4+r), col=lr / 16+lr)
    unsigned short* trw = tr[w][tt&1];
    #pragma unroll
    for (int r=0;r<4;r++){
      int row = lg*4 + r;
      trw[row*40 + lr]      = bf16_rne(fmaxf(acc1a[r], 0.f));
      trw[row*40 + 16 + lr] = bf16_rne(fmaxf(acc1b[r], 0.f));
    }
    // layer 2: A-frag from transpose tile (row=lr, k=lg*8..+7), one MFMA
    bf16x8 a2 = *(const bf16x8*)&trw[lr*40 + lg*8];
    f32x4 acc2 = (f32x4){b2v,b2v,b2v,b2v};
    acc2 = __builtin_amdgcn_mfma_f32_16x16x32_bf16(a2, w2f, acc2, 0,0,0);
    // layer 3: relu * w3, butterfly over the 16 cols
    f32x4 val;
    #pragma unroll
    for (int r=0;r<4;r++) val[r] = fmaxf(acc2[r], 0.f) * w3v;
    #pragma unroll
    for (int off=1; off<16; off<<=1){
      #pragma unroll
      for (int r=0;r<4;r++) val[r] += __shfl_xor(val[r], off);
    }
    // softplus + /cap, sum 4 rows per lane, fold half-paths, store 2 paths/tile
    float dsum = 0.f;
    #pragma unroll
    for (int r=0;r<4;r++){
      size_t grow = rowbase + lg*4 + r;
      float o = val[r] + b3v;
      float sp = (o > 20.f) ? o : log1pf(__expf(o));
      dsum += sp * __builtin_amdgcn_rcpf(cap[ltp[grow]]);
    }
    dsum += __shfl_xor(dsum, 16);
    if (lr == 0 && (lg & 1) == 0)
      out[(rowbase >> 3) + (lg >> 1)] = dsum;
  }
}

extern "C" void kernel_launch(void* const* d_in, const int* in_sizes, int n_in,
                              void* d_out, int out_size, void* d_ws, size_t ws_size,
                              hipStream_t stream) {
  const float* ft    = (const float*)d_in[0];
  const float* fpk   = (const float*)d_in[1];
  const float* fps   = (const float*)d_in[2];
  const float* cap   = (const float*)d_in[3];
  const int*   ltp   = (const int*)  d_in[4];
  const int*   ptl   = (const int*)  d_in[5];
  const float* pe_w1 = (const float*)d_in[6];
  const float* pe_b1 = (const float*)d_in[7];
  const float* pe_w2 = (const float*)d_in[8];
  const float* pe_b2 = (const float*)d_in[9];
  const float* le_w1 = (const float*)d_in[10];
  const float* le_b1 = (const float*)d_in[11];
  const float* le_w2 = (const float*)d_in[12];
  const float* le_b2 = (const float*)d_in[13];
  const float* pg_wx = (const float*)d_in[14];
  const float* pg_wh = (const float*)d_in[15];
  const float* pg_bx = (const float*)d_in[16];
  const float* pg_bh = (const float*)d_in[17];
  const float* lg_wx = (const float*)d_in[18];
  const float* lg_wh = (const float*)d_in[19];
  const float* lg_bx = (const float*)d_in[20];
  const float* lg_bh = (const float*)d_in[21];
  const float* ro_w1 = (const float*)d_in[22];
  const float* ro_b1 = (const float*)d_in[23];
  const float* ro_w2 = (const float*)d_in[24];
  const float* ro_b2 = (const float*)d_in[25];
  const float* ro_w3 = (const float*)d_in[26];
  const float* ro_b3 = (const float*)d_in[27];
  float* out = (float*)d_out;

  float* path_state = (float*)d_ws;
  float* link_state = path_state + (size_t)N_PATHS*DIM;
  unsigned short* LXq   = (unsigned short*)(link_state + (size_t)N_LINKS*DIM);
  unsigned short* seq16 = LXq + (size_t)N_LINKS*G3;
  unsigned short* whf   = seq16 + (size_t)N_PATHS*LPATH*DIM;   // 51712 ushorts

  path_embed<<<N_PATHS/4, 256, 0, stream>>>(ft, fpk, fps, pe_w1, pe_b1, pe_w2, pe_b2, path_state);
  link_embed<<<N_LINKS/4, 256, 0, stream>>>(ft, cap, ptl, le_w1, le_b1, le_w2, le_b2, link_state);
  pack_frags<<<202, 256, 0, stream>>>(pg_wh, pg_wx, lg_wx, lg_wh, ro_w1, ro_w2, whf);
  compute_lx<<<N_LINKS/4, 192, 0, stream>>>(link_state, pg_wx, pg_bx, pg_bh, LXq);
  for (int it=0; it<ITERS; ++it){
    path_scan_mfma<<<N_PATHS/16, 256, 0, stream>>>(LXq, ltp, whf, pg_bh, path_state, seq16);
    if (it < ITERS-1)
      link_fused<<<N_LINKS/16, 256, 0, stream>>>(seq16, ptl, whf,
          lg_bx, lg_bh, pg_bx, pg_bh, link_state, LXq);
  }
  readout<<<(N_PATHS*LPATH + 255)/256, 256, 0, stream>>>(seq16, ltp, cap, whf,
      ro_b1, ro_b2, ro_w3, ro_b3, out);
}